// Round 3
// baseline (5157.683 us; speedup 1.0000x reference)
//
#include <hip/hip_runtime.h>
#include <math.h>

// B=32 S=512 H=2048 NH=8 HD=256.
// R2 post-mortem: NaN survived staging+ws fixes => input-dtype was wrong.
// Inputs/output are FP32 per the reference (harness: "float32 -> const float*").
// Internal activations bf16 (MFMA), fp32 accum, fp32 final output.
// Scratch: ws peak 128 MiB (RA/RB 64 MiB each); d_out doubles as scratch
// (Pc/VTc in attention, R1 then F1 chunks after) before the final fp32 write.

typedef __bf16 bf16;
typedef __bf16 bf16x8 __attribute__((ext_vector_type(8)));
typedef float f32x4 __attribute__((ext_vector_type(4)));

#define Hdim 2048

// ---------------------------------------------------------------------------
// Batched GEMM: C[m,n] = act(scale*sum_k A[m,k]*W[n,k] + bias[n] + res[m,n])
// A: bf16 [M,K] row-major. W: bf16 or fp32 (WF) [N,K] row-major. C: bf16.
// bias: fp32 or null. res: fp32 (RF=1) / bf16 (RF=0) or null.
// Batch offsets (elements): ptr += (z/zd)*s1 + (z%zd)*s2.
// BM=BN=128, BK=64; 256 thr = 4 waves 2x2; 4x4 frags of 16x16x32 MFMA.
// ---------------------------------------------------------------------------
template <int WF, int RF>
__global__ __launch_bounds__(256)
void gemm_bt(const bf16* __restrict__ A, int lda, long sA1, long sA2, int zdA,
             const void* __restrict__ Wp, int ldw, long sW1, long sW2, int zdW,
             bf16* __restrict__ C, int ldc, long sC1, long sC2, int zdC,
             const float* __restrict__ bias,
             const void* __restrict__ resp, int ldr,
             int K, float scale, int act)
{
  __shared__ bf16 As[128 * 64];
  __shared__ bf16 Ws[128 * 64];
  const int tid = threadIdx.x;
  const int z = blockIdx.z;
  A += (size_t)(z / zdA) * sA1 + (size_t)(z % zdA) * sA2;
  const size_t woff = (size_t)(z / zdW) * sW1 + (size_t)(z % zdW) * sW2;
  C += (size_t)(z / zdC) * sC1 + (size_t)(z % zdC) * sC2;
  const int m0 = blockIdx.y * 128, n0 = blockIdx.x * 128;
  const int sm = tid >> 3;          // staging row 0..31 (+32 per sweep)
  const int sk = (tid & 7) * 8;     // staging k-offset (elements)
  const int lane = tid & 63, quad = lane >> 4, lr = lane & 15;
  const int wid = tid >> 6, wm = wid >> 1, wn = wid & 1;

  f32x4 acc[4][4] = {};

  const bf16* Ag = A + (size_t)(m0 + sm) * lda + sk;
  const bf16* Wg16 = (const bf16*)Wp + woff + (size_t)(n0 + sm) * ldw + sk;
  const float* Wg32 = (const float*)Wp + woff + (size_t)(n0 + sm) * ldw + sk;

  for (int k0 = 0; k0 < K; k0 += 64) {
    uint4 av[4];
    bf16x8 wv[4];
#pragma unroll
    for (int s = 0; s < 4; ++s) {
      av[s] = *(const uint4*)(Ag + (size_t)(s * 32) * lda + k0);
      if (WF) {
        float4 w0 = *(const float4*)(Wg32 + (size_t)(s * 32) * ldw + k0);
        float4 w1 = *(const float4*)(Wg32 + (size_t)(s * 32) * ldw + k0 + 4);
        wv[s][0] = (bf16)w0.x; wv[s][1] = (bf16)w0.y;
        wv[s][2] = (bf16)w0.z; wv[s][3] = (bf16)w0.w;
        wv[s][4] = (bf16)w1.x; wv[s][5] = (bf16)w1.y;
        wv[s][6] = (bf16)w1.z; wv[s][7] = (bf16)w1.w;
      } else {
        wv[s] = *(const bf16x8*)(Wg16 + (size_t)(s * 32) * ldw + k0);
      }
    }
#pragma unroll
    for (int s = 0; s < 4; ++s) {
      *(uint4*)&As[s * 2048 + tid * 8] = av[s];
      *(bf16x8*)&Ws[s * 2048 + tid * 8] = wv[s];
    }
    __syncthreads();
#pragma unroll
    for (int kk = 0; kk < 64; kk += 32) {
      bf16x8 af[4], bfr[4];
#pragma unroll
      for (int i = 0; i < 4; ++i)
        af[i] = *(const bf16x8*)&As[(wm * 64 + i * 16 + lr) * 64 + kk + quad * 8];
#pragma unroll
      for (int j = 0; j < 4; ++j)
        bfr[j] = *(const bf16x8*)&Ws[(wn * 64 + j * 16 + lr) * 64 + kk + quad * 8];
#pragma unroll
      for (int i = 0; i < 4; ++i)
#pragma unroll
        for (int j = 0; j < 4; ++j)
          acc[i][j] = __builtin_amdgcn_mfma_f32_16x16x32_bf16(af[i], bfr[j], acc[i][j], 0, 0, 0);
    }
    __syncthreads();
  }

  float bj[4];
#pragma unroll
  for (int j = 0; j < 4; ++j)
    bj[j] = bias ? bias[n0 + wn * 64 + j * 16 + lr] : 0.0f;

#pragma unroll
  for (int i = 0; i < 4; ++i) {
#pragma unroll
    for (int r = 0; r < 4; ++r) {
      const int m = m0 + wm * 64 + i * 16 + quad * 4 + r;   // C/D: row = quad*4+reg
#pragma unroll
      for (int j = 0; j < 4; ++j) {
        const int n = n0 + wn * 64 + j * 16 + lr;           // C/D: col = lane&15
        float v = acc[i][j][r] * scale + bj[j];
        if (resp) {
          if (RF) v += ((const float*)resp)[(size_t)m * ldr + n];
          else    v += (float)((const bf16*)resp)[(size_t)m * ldr + n];
        }
        if (act == 1) v = fmaxf(v, 0.0f);
        else if (act == 2) v = 0.5f * v * (1.0f + erff(v * 0.70710678118654752f));
        C[(size_t)m * ldc + n] = (bf16)v;
      }
    }
  }
}

// X(bf16) = emb(fp32) + pe(fp32)[idx] — one block per token row
__global__ __launch_bounds__(256)
void gather_pe(const float* __restrict__ emb, const int* __restrict__ idx,
               const float* __restrict__ pe, bf16* __restrict__ X)
{
  const int m = blockIdx.x;
  const int p = idx[m];
  const size_t off = (size_t)m * Hdim + threadIdx.x * 8;
  const size_t poff = (size_t)p * Hdim + threadIdx.x * 8;
  float4 e0 = *(const float4*)&emb[off];
  float4 e1 = *(const float4*)&emb[off + 4];
  float4 q0 = *(const float4*)&pe[poff];
  float4 q1 = *(const float4*)&pe[poff + 4];
  bf16x8 o;
  o[0] = (bf16)(e0.x + q0.x); o[1] = (bf16)(e0.y + q0.y);
  o[2] = (bf16)(e0.z + q0.z); o[3] = (bf16)(e0.w + q0.w);
  o[4] = (bf16)(e1.x + q1.x); o[5] = (bf16)(e1.y + q1.y);
  o[6] = (bf16)(e1.z + q1.z); o[7] = (bf16)(e1.w + q1.w);
  *(bf16x8*)&X[off] = o;
}

// row-softmax over 512 cols in place (bf16); one wave per row
__global__ __launch_bounds__(256)
void softmax_rows(bf16* __restrict__ P)
{
  const int lane = threadIdx.x & 63;
  const size_t row = (size_t)blockIdx.x * 4 + (threadIdx.x >> 6);
  bf16* p = P + row * 512 + lane * 8;
  bf16x8 v = *(const bf16x8*)p;
  float x[8], mx = -1e30f;
#pragma unroll
  for (int j = 0; j < 8; ++j) { x[j] = (float)v[j]; mx = fmaxf(mx, x[j]); }
#pragma unroll
  for (int o = 32; o; o >>= 1) mx = fmaxf(mx, __shfl_xor(mx, o));
  float s = 0.0f;
#pragma unroll
  for (int j = 0; j < 8; ++j) { x[j] = expf(x[j] - mx); s += x[j]; }
#pragma unroll
  for (int o = 32; o; o >>= 1) s += __shfl_xor(s, o);
  const float inv = 1.0f / s;
  bf16x8 ov;
#pragma unroll
  for (int j = 0; j < 8; ++j) ov[j] = (bf16)(x[j] * inv);
  *(bf16x8*)p = ov;
}

// per-(b_local,h) transpose V[512,256] (bf16, row stride 6144 in QKVc) -> VT[256,512]
__global__ __launch_bounds__(256)
void transpose_v(const bf16* __restrict__ qkv, bf16* __restrict__ vt)
{
  const int z = blockIdx.z, b = z >> 3, h = z & 7;
  const unsigned short* V =
      (const unsigned short*)qkv + (size_t)b * 512 * 6144 + 4096 + h * 256;
  unsigned short* out = (unsigned short*)vt + (size_t)z * 256 * 512;
  const int d0 = blockIdx.x * 64, k0 = blockIdx.y * 64;
  __shared__ unsigned short t[64 * 65];
  const int r = threadIdx.x >> 3;
  const int c8 = (threadIdx.x & 7) * 8;
#pragma unroll
  for (int pass = 0; pass < 2; ++pass) {
    const int rr = r + pass * 32;
    uint4 u = *(const uint4*)(V + (size_t)(k0 + rr) * 6144 + d0 + c8);
    const unsigned short* ep = (const unsigned short*)&u;
#pragma unroll
    for (int j = 0; j < 8; ++j) t[(c8 + j) * 65 + rr] = ep[j];
  }
  __syncthreads();
#pragma unroll
  for (int pass = 0; pass < 2; ++pass) {
    const int dr = r + pass * 32;
    unsigned short e[8];
#pragma unroll
    for (int j = 0; j < 8; ++j) e[j] = t[dr * 65 + c8 + j];
    *(uint4*)(out + (size_t)(d0 + dr) * 512 + k0 + c8) = *(const uint4*)e;
  }
}

// LayerNorm over H=2048: bf16 src -> bf16 dst, fp32 g/b; one block per row
__global__ __launch_bounds__(256)
void ln_rows(const bf16* __restrict__ src, const float* __restrict__ g,
             const float* __restrict__ b, bf16* __restrict__ dst)
{
  const size_t off = (size_t)blockIdx.x * Hdim + threadIdx.x * 8;
  bf16x8 v = *(const bf16x8*)&src[off];
  float x[8], s = 0.0f, ss = 0.0f;
#pragma unroll
  for (int j = 0; j < 8; ++j) { x[j] = (float)v[j]; s += x[j]; ss += x[j] * x[j]; }
  __shared__ float red[8];
#pragma unroll
  for (int o = 32; o; o >>= 1) { s += __shfl_xor(s, o); ss += __shfl_xor(ss, o); }
  const int w = threadIdx.x >> 6;
  if ((threadIdx.x & 63) == 0) { red[w] = s; red[4 + w] = ss; }
  __syncthreads();
  s = red[0] + red[1] + red[2] + red[3];
  ss = red[4] + red[5] + red[6] + red[7];
  const float mean = s * (1.0f / Hdim);
  const float var = ss * (1.0f / Hdim) - mean * mean;
  const float rstd = rsqrtf(var + 1e-5f);
  float4 g0 = *(const float4*)&g[threadIdx.x * 8];
  float4 g1 = *(const float4*)&g[threadIdx.x * 8 + 4];
  float4 b0 = *(const float4*)&b[threadIdx.x * 8];
  float4 b1 = *(const float4*)&b[threadIdx.x * 8 + 4];
  const float gg[8] = {g0.x, g0.y, g0.z, g0.w, g1.x, g1.y, g1.z, g1.w};
  const float bb[8] = {b0.x, b0.y, b0.z, b0.w, b1.x, b1.y, b1.z, b1.w};
  bf16x8 ov;
#pragma unroll
  for (int j = 0; j < 8; ++j)
    ov[j] = (bf16)(((x[j] - mean) * rstd) * gg[j] + bb[j]);
  *(bf16x8*)&dst[off] = ov;
}

// OUT(fp32) = x / max(||x||_2, 1e-12) per row; bf16 src
__global__ __launch_bounds__(256)
void l2norm_rows(const bf16* __restrict__ src, float* __restrict__ dst)
{
  const size_t off = (size_t)blockIdx.x * Hdim + threadIdx.x * 8;
  bf16x8 v = *(const bf16x8*)&src[off];
  float x[8], ss = 0.0f;
#pragma unroll
  for (int j = 0; j < 8; ++j) { x[j] = (float)v[j]; ss += x[j] * x[j]; }
  __shared__ float red[4];
#pragma unroll
  for (int o = 32; o; o >>= 1) ss += __shfl_xor(ss, o);
  const int w = threadIdx.x >> 6;
  if ((threadIdx.x & 63) == 0) red[w] = ss;
  __syncthreads();
  ss = red[0] + red[1] + red[2] + red[3];
  const float inv = 1.0f / fmaxf(sqrtf(ss), 1e-12f);
  float4 o0, o1;
  o0.x = x[0] * inv; o0.y = x[1] * inv; o0.z = x[2] * inv; o0.w = x[3] * inv;
  o1.x = x[4] * inv; o1.y = x[5] * inv; o1.z = x[6] * inv; o1.w = x[7] * inv;
  *(float4*)&dst[off] = o0;
  *(float4*)&dst[off + 4] = o1;
}

// ---------------------------------------------------------------------------
extern "C" void kernel_launch(void* const* d_in, const int* in_sizes, int n_in,
                              void* d_out, int out_size, void* d_ws, size_t ws_size,
                              hipStream_t stream)
{
  const float* emb  = (const float*)d_in[0];
  const int*   tix  = (const int*)d_in[1];
  const float* pe   = (const float*)d_in[2];
  const float* Wqkv = (const float*)d_in[3];
  const float* Bqkv = (const float*)d_in[4];
  const float* Wout = (const float*)d_in[5];
  const float* Bout = (const float*)d_in[6];
  const float* ln1g = (const float*)d_in[7];
  const float* ln1b = (const float*)d_in[8];
  const float* Wff1 = (const float*)d_in[9];
  const float* Bff1 = (const float*)d_in[10];
  const float* Wff2 = (const float*)d_in[11];
  const float* Bff2 = (const float*)d_in[12];
  const float* ln2g = (const float*)d_in[13];
  const float* ln2b = (const float*)d_in[14];
  const float* Wte1 = (const float*)d_in[15];
  const float* Bte1 = (const float*)d_in[16];
  const float* Wte2 = (const float*)d_in[17];
  const float* Bte2 = (const float*)d_in[18];
  const float* Wpr1 = (const float*)d_in[19];
  const float* Bpr1 = (const float*)d_in[20];
  const float* Wpr2 = (const float*)d_in[21];
  const float* Bpr2 = (const float*)d_in[22];
  float* OUT = (float*)d_out;

  // ws (128 MiB): RA [0,64M) X->O(row-aliased)->H1->H2->TE->PR (bf16)
  //               RB [64M,128M) QKVc(48M)->R2->TM->PM (bf16)
  // d_out (128 MiB fp32) as scratch: attention Pc[0,32M)+VTc[32M,48M);
  //   then R1 bf16 [0,64M); then F1 chunks bf16 [0,32M); final fp32 OUT.
  char* w = (char*)d_ws;
  bf16* RA   = (bf16*)(w);
  bf16* RB   = (bf16*)(w + (64u << 20));
  bf16* QKVc = RB;
  char* ob   = (char*)d_out;
  bf16* Pc   = (bf16*)(ob);
  bf16* VTc  = (bf16*)(ob + (32u << 20));
  bf16* R1   = (bf16*)(ob);
  bf16* F1c  = (bf16*)(ob);

  // 1. X = emb + pe[idx]
  gather_pe<<<16384, 256, 0, stream>>>(emb, tix, pe, RA);

  // 2-6. attention: 4 chunks of 8 batches (4096 rows, 64 (b,h) pairs each)
  for (int c = 0; c < 4; ++c) {
    const bf16* Xc = RA + (size_t)c * 4096 * 2048;
    bf16* Oc = RA + (size_t)c * 4096 * 2048;   // O rows alias dead X rows

    // QKVc = Xc @ Wqkv^T + Bqkv   [4096,6144]
    gemm_bt<1, 0><<<dim3(48, 32, 1), 256, 0, stream>>>(
        Xc, 2048, 0, 0, 1, Wqkv, 2048, 0, 0, 1, QKVc, 6144, 0, 0, 1,
        Bqkv, nullptr, 0, 2048, 1.0f, 0);

    // Pc[z] = Q K^T / 16,  z = b_local*8 + h
    gemm_bt<0, 0><<<dim3(4, 4, 64), 256, 0, stream>>>(
        QKVc, 6144, 3145728L, 256, 8,
        QKVc + 2048, 6144, 3145728L, 256, 8,
        Pc, 512, 262144L, 0, 1,
        nullptr, nullptr, 0, 256, 0.0625f, 0);

    softmax_rows<<<8192, 256, 0, stream>>>(Pc);

    transpose_v<<<dim3(4, 8, 64), 256, 0, stream>>>(QKVc, VTc);

    // Oc = Pc @ V
    gemm_bt<0, 0><<<dim3(2, 4, 64), 256, 0, stream>>>(
        Pc, 512, 262144L, 0, 1,
        VTc, 512, 131072L, 0, 1,
        Oc, 2048, 1048576L, 256, 8,
        nullptr, nullptr, 0, 512, 1.0f, 0);
  }

  // 7. R1 = O @ Wout^T + Bout + emb(fp32 residual)   (R1 in d_out scratch)
  gemm_bt<1, 1><<<dim3(16, 128, 1), 256, 0, stream>>>(
      RA, 2048, 0, 0, 1, Wout, 2048, 0, 0, 1, R1, 2048, 0, 0, 1,
      Bout, emb, 2048, 2048, 1.0f, 0);

  // 8. H1 = LN(R1) -> RA (O dead)
  ln_rows<<<16384, 256, 0, stream>>>(R1, ln1g, ln1b, RA);

  // 9-10. FFN in 8 row-chunks of 2048 rows; F1c in d_out (R1 dead); R2 -> RB
  for (int f = 0; f < 8; ++f) {
    const bf16* H1f = RA + (size_t)f * 2048 * 2048;
    bf16* R2f = RB + (size_t)f * 2048 * 2048;
    gemm_bt<1, 0><<<dim3(64, 16, 1), 256, 0, stream>>>(
        H1f, 2048, 0, 0, 1, Wff1, 2048, 0, 0, 1, F1c, 8192, 0, 0, 1,
        Bff1, nullptr, 0, 2048, 1.0f, 2);
    gemm_bt<1, 0><<<dim3(16, 16, 1), 256, 0, stream>>>(
        F1c, 8192, 0, 0, 1, Wff2, 8192, 0, 0, 1, R2f, 2048, 0, 0, 1,
        Bff2, H1f, 2048, 8192, 1.0f, 0);
  }

  // 11. H2 = LN(R2) -> RA (H1 dead)
  ln_rows<<<16384, 256, 0, stream>>>(RB, ln2g, ln2b, RA);

  // 12. TM = relu(H2 @ Wte1^T + Bte1) -> RB
  gemm_bt<1, 0><<<dim3(16, 128, 1), 256, 0, stream>>>(
      RA, 2048, 0, 0, 1, Wte1, 2048, 0, 0, 1, RB, 2048, 0, 0, 1,
      Bte1, nullptr, 0, 2048, 1.0f, 1);

  // 13. TE = TM @ Wte2^T + Bte2 -> RA
  gemm_bt<1, 0><<<dim3(16, 128, 1), 256, 0, stream>>>(
      RB, 2048, 0, 0, 1, Wte2, 2048, 0, 0, 1, RA, 2048, 0, 0, 1,
      Bte2, nullptr, 0, 2048, 1.0f, 0);

  // 14. PM = relu(TE @ Wpr1^T + Bpr1) -> RB
  gemm_bt<1, 0><<<dim3(16, 128, 1), 256, 0, stream>>>(
      RA, 2048, 0, 0, 1, Wpr1, 2048, 0, 0, 1, RB, 2048, 0, 0, 1,
      Bpr1, nullptr, 0, 2048, 1.0f, 1);

  // 15. PR = PM @ Wpr2^T + Bpr2 -> RA
  gemm_bt<1, 0><<<dim3(16, 128, 1), 256, 0, stream>>>(
      RB, 2048, 0, 0, 1, Wpr2, 2048, 0, 0, 1, RA, 2048, 0, 0, 1,
      Bpr2, nullptr, 0, 2048, 1.0f, 0);

  // 16. OUT(fp32) = l2norm(PR)
  l2norm_rows<<<16384, 256, 0, stream>>>(RA, OUT);
}